// Round 1
// baseline (96.833 us; speedup 1.0000x reference)
//
#include <hip/hip_runtime.h>

// SelfAttentionBlock collapses algebraically:
//   softmax rows sum to 1; einsum('btu,btj->btj', w, v) = (sum_u w)·v = v
//   =>  out = x @ Wv^T + bv.   M=8192, K=1024, N=64. fp32 in, fp32 out.
//
// History: round-1 NaN proved inputs are fp32; round-5 PASS (absmax 0.03125)
// proved fp32 output + the documented MFMA mapping (A/B frag k = quad*8+j
// contiguous; C/D row = quad*4+reg, col = lane&15). This round: the two
// 43.4 µs / 256 MB workspace-poison fills in the timed graph are an ~87 µs
// floor; the controllable remainder is the cvt_w launch + its dependency
// stall. So: single fused kernel, Wv converted fp32->bf16 inline (B-side L2
// traffic doubles to 128 MB but overlaps the 5.4 µs HBM x-stream), zero
// workspace use.

#define K_DIM 1024
#define N_DIM 64

typedef __attribute__((ext_vector_type(4))) float f32x4;
typedef __attribute__((ext_vector_type(8))) short s16x8;   // 8 bf16 frag

__device__ __forceinline__ short f2bf(float f) {
    // round-to-nearest-even fp32 -> bf16 (inputs finite)
    union { float f; unsigned u; } v{f};
    unsigned r = v.u + 0x7FFFu + ((v.u >> 16) & 1u);
    return (short)(r >> 16);
}

// ---- v = x @ Wv^T + bv. 512 blocks x 256 thr; block = 16-row M-tile;
// split-K=4 across the 4 waves (256 K each); LDS cross-wave reduce.
// B (Wv) loaded fp32 direct from d_in, converted inline — no pre-pass.
__global__ __launch_bounds__(256, 2) void vproj_kernel(
    const float* __restrict__ x,               // [8192][1024] fp32
    const float* __restrict__ wv,              // [64][1024] fp32
    const float* __restrict__ bv,              // [64] fp32
    float* __restrict__ out)                   // [8192][64] fp32
{
    const int tid  = threadIdx.x;
    const int wave = tid >> 6;        // 0..3 — K-chunk owner
    const int lane = tid & 63;
    const int quad = lane >> 4;       // 0..3
    const int l16  = lane & 15;

    const int mt  = blockIdx.x;               // 0..511
    const int row = (mt << 4) + l16;          // A row m = lane&15

    // A frag element j = x[row][kb + j] (contiguous 8); B: Wv[l16+16t][same].
    const int kb = (wave << 8) + (quad << 3);

    const float* ap  = x  + row * K_DIM + kb;
    const float* bp0 = wv + (l16     ) * K_DIM + kb;
    const float* bp1 = wv + (l16 + 16) * K_DIM + kb;
    const float* bp2 = wv + (l16 + 32) * K_DIM + kb;
    const float* bp3 = wv + (l16 + 48) * K_DIM + kb;

    f32x4 acc0 = {0.f, 0.f, 0.f, 0.f};
    f32x4 acc1 = acc0, acc2 = acc0, acc3 = acc0;

#pragma unroll
    for (int ks = 0; ks < 8; ++ks) {
        const int o = ks * 32;                 // 32 K-elements per MFMA step
        f32x4 a0  = *(const f32x4*)(ap  + o);
        f32x4 a1  = *(const f32x4*)(ap  + o + 4);
        f32x4 c00 = *(const f32x4*)(bp0 + o);  // L2-hit fp32 Wv loads
        f32x4 c01 = *(const f32x4*)(bp0 + o + 4);
        f32x4 c10 = *(const f32x4*)(bp1 + o);
        f32x4 c11 = *(const f32x4*)(bp1 + o + 4);
        f32x4 c20 = *(const f32x4*)(bp2 + o);
        f32x4 c21 = *(const f32x4*)(bp2 + o + 4);
        f32x4 c30 = *(const f32x4*)(bp3 + o);
        f32x4 c31 = *(const f32x4*)(bp3 + o + 4);
        s16x8 a, b0, b1, b2, b3;
#pragma unroll
        for (int j = 0; j < 4; ++j) {
            a[j]  = f2bf(a0[j]);   a[4 + j]  = f2bf(a1[j]);
            b0[j] = f2bf(c00[j]);  b0[4 + j] = f2bf(c01[j]);
            b1[j] = f2bf(c10[j]);  b1[4 + j] = f2bf(c11[j]);
            b2[j] = f2bf(c20[j]);  b2[4 + j] = f2bf(c21[j]);
            b3[j] = f2bf(c30[j]);  b3[4 + j] = f2bf(c31[j]);
        }
        acc0 = __builtin_amdgcn_mfma_f32_16x16x32_bf16(a, b0, acc0, 0, 0, 0);
        acc1 = __builtin_amdgcn_mfma_f32_16x16x32_bf16(a, b1, acc1, 0, 0, 0);
        acc2 = __builtin_amdgcn_mfma_f32_16x16x32_bf16(a, b2, acc2, 0, 0, 0);
        acc3 = __builtin_amdgcn_mfma_f32_16x16x32_bf16(a, b3, acc3, 0, 0, 0);
    }

    // Cross-wave (split-K) reduction. C/D: row = quad*4+reg, col = lane&15.
    __shared__ float red[4][16][N_DIM + 1];
    const int r0 = quad << 2;
#pragma unroll
    for (int r = 0; r < 4; ++r) {
        red[wave][r0 + r][l16     ] = acc0[r];
        red[wave][r0 + r][l16 + 16] = acc1[r];
        red[wave][r0 + r][l16 + 32] = acc2[r];
        red[wave][r0 + r][l16 + 48] = acc3[r];
    }
    __syncthreads();

    const int c   = tid & 63;                 // output col, coalesced store
    const int rr0 = tid >> 6;                 // rows rr0, rr0+4, rr0+8, rr0+12
    const float bias = bv[c];
#pragma unroll
    for (int i = 0; i < 4; ++i) {
        const int r = rr0 + (i << 2);
        const float s = red[0][r][c] + red[1][r][c] + red[2][r][c]
                      + red[3][r][c] + bias;
        out[((mt << 4) + r) * N_DIM + c] = s;
    }
}

extern "C" void kernel_launch(void* const* d_in, const int* in_sizes, int n_in,
                              void* d_out, int out_size, void* d_ws, size_t ws_size,
                              hipStream_t stream) {
    // dict order: 0:x 1:Wq 2:bq 3:Wk 4:bk 5:Wv 6:bv (size-checked for safety).
    int ix = 0, iw = -1, ib = -1;
    for (int i = 0; i < n_in; ++i) {
        if      (in_sizes[i] == 8388608) ix = i;
        else if (in_sizes[i] == 65536)   iw = i;   // keeps last (= Wv)
        else if (in_sizes[i] == 64)      ib = i;   // keeps last (= bv)
    }
    if (iw < 0) iw = 5;
    if (ib < 0) ib = 6;

    const float* x  = (const float*)d_in[ix];
    const float* Wv = (const float*)d_in[iw];
    const float* bv = (const float*)d_in[ib];
    float* out = (float*)d_out;
    (void)d_ws; (void)ws_size;                 // workspace unused now

    vproj_kernel<<<512, 256, 0, stream>>>(x, Wv, bv, out);
}

// Round 2
// 92.194 us; speedup vs baseline: 1.0503x; 1.0503x over previous
//
#include <hip/hip_runtime.h>
#include <hip/hip_bf16.h>

// SelfAttentionBlock collapses algebraically:
//   softmax rows sum to 1; einsum('btu,btj->btj', w, v) = (sum_u w)·v = v
//   =>  out = x @ Wv^T + bv.   M=8192, K=1024, N=64. fp32 in, FP32 out.
//
// Measurement model (established rounds 0-1): the timed graph contains
// ~86.8 µs of fixed harness workspace-poison fills (2 × 256 MB @ 43.4 µs,
// present whether or not d_ws is used). Controllable kernel time is ~4.2 µs
// (cvt ~1 µs + vproj ~3 µs; x is L3-resident so vproj runs at Infinity-Cache
// speed, under the 5.4 µs HBM roofline). Round-1 experiment: fusing the
// Wv fp32->bf16 convert into vproj REGRESSED +5.9 µs (fp32 B doubles L2
// traffic to 128 MB and puts 5x f2bf VALU on the MFMA dependency chain).
// Conclusion: the two-kernel structure below is within ~1.5 µs of the
// kernel-side floor; this is the revert to the measured-90.96 source.

#define K_DIM 1024
#define N_DIM 64

typedef __attribute__((ext_vector_type(4))) float f32x4;
typedef __attribute__((ext_vector_type(8))) short s16x8;   // 8 bf16 frag
typedef __attribute__((ext_vector_type(4))) short s16x4;

__device__ __forceinline__ short f2bf(float f) {
    // round-to-nearest-even fp32 -> bf16 (inputs finite)
    union { float f; unsigned u; } v{f};
    unsigned r = v.u + 0x7FFFu + ((v.u >> 16) & 1u);
    return (short)(r >> 16);
}

// ---- Pre-pass: Wv fp32 [64][1024] -> bf16 in d_ws (L2-resident, 128 KB).
__global__ __launch_bounds__(256) void cvt_w_kernel(
    const float* __restrict__ w, short* __restrict__ o) {
    const int i = (blockIdx.x * 256 + threadIdx.x) * 4;   // 64 blocks -> 65536
    f32x4 v = *(const f32x4*)(w + i);
    s16x4 r;
#pragma unroll
    for (int j = 0; j < 4; ++j) r[j] = f2bf(v[j]);
    *(s16x4*)(o + i) = r;
}

// ---- Main: v = x @ Wv^T + bv. 512 blocks x 256 thr; block = 16-row
// M-tile; split-K=4 across the 4 waves (256 K each); LDS cross-wave reduce.
__global__ __launch_bounds__(256, 2) void vproj_kernel(
    const float* __restrict__ x,               // [8192][1024] fp32
    const short* __restrict__ wbf,             // [64][1024] bf16
    const float* __restrict__ bv,              // [64] fp32
    float* __restrict__ out)                   // [8192][64] fp32
{
    const int tid  = threadIdx.x;
    const int wave = tid >> 6;        // 0..3 — K-chunk owner
    const int lane = tid & 63;
    const int quad = lane >> 4;       // 0..3
    const int l16  = lane & 15;

    const int mt  = blockIdx.x;               // 0..511
    const int row = (mt << 4) + l16;          // A row m = lane&15

    // A frag element j = x[row][kb + j] (contiguous 8); B: Wv[l16+16t][same].
    const int kb = (wave << 8) + (quad << 3);

    const float* ap  = x   + row * K_DIM + kb;
    const short* bp0 = wbf + (l16     ) * K_DIM + kb;
    const short* bp1 = wbf + (l16 + 16) * K_DIM + kb;
    const short* bp2 = wbf + (l16 + 32) * K_DIM + kb;
    const short* bp3 = wbf + (l16 + 48) * K_DIM + kb;

    f32x4 acc0 = {0.f, 0.f, 0.f, 0.f};
    f32x4 acc1 = acc0, acc2 = acc0, acc3 = acc0;

#pragma unroll
    for (int ks = 0; ks < 8; ++ks) {
        const int o = ks * 32;                 // 32 K-elements per MFMA step
        f32x4 a0 = *(const f32x4*)(ap + o);
        f32x4 a1 = *(const f32x4*)(ap + o + 4);
        s16x8 b0 = *(const s16x8*)(bp0 + o);   // single 16 B L2-hit load
        s16x8 b1 = *(const s16x8*)(bp1 + o);
        s16x8 b2 = *(const s16x8*)(bp2 + o);
        s16x8 b3 = *(const s16x8*)(bp3 + o);
        s16x8 a;
#pragma unroll
        for (int j = 0; j < 4; ++j) { a[j] = f2bf(a0[j]); a[4 + j] = f2bf(a1[j]); }
        acc0 = __builtin_amdgcn_mfma_f32_16x16x32_bf16(a, b0, acc0, 0, 0, 0);
        acc1 = __builtin_amdgcn_mfma_f32_16x16x32_bf16(a, b1, acc1, 0, 0, 0);
        acc2 = __builtin_amdgcn_mfma_f32_16x16x32_bf16(a, b2, acc2, 0, 0, 0);
        acc3 = __builtin_amdgcn_mfma_f32_16x16x32_bf16(a, b3, acc3, 0, 0, 0);
    }

    // Cross-wave (split-K) reduction. C/D: row = quad*4+reg, col = lane&15.
    __shared__ float red[4][16][N_DIM + 1];
    const int r0 = quad << 2;
#pragma unroll
    for (int r = 0; r < 4; ++r) {
        red[wave][r0 + r][l16     ] = acc0[r];
        red[wave][r0 + r][l16 + 16] = acc1[r];
        red[wave][r0 + r][l16 + 32] = acc2[r];
        red[wave][r0 + r][l16 + 48] = acc3[r];
    }
    __syncthreads();

    const int c   = tid & 63;                 // output col, coalesced store
    const int rr0 = tid >> 6;                 // rows rr0, rr0+4, rr0+8, rr0+12
    const float bias = bv[c];
#pragma unroll
    for (int i = 0; i < 4; ++i) {
        const int r = rr0 + (i << 2);
        const float s = red[0][r][c] + red[1][r][c] + red[2][r][c]
                      + red[3][r][c] + bias;
        out[((mt << 4) + r) * N_DIM + c] = s;
    }
}

extern "C" void kernel_launch(void* const* d_in, const int* in_sizes, int n_in,
                              void* d_out, int out_size, void* d_ws, size_t ws_size,
                              hipStream_t stream) {
    // dict order: 0:x 1:Wq 2:bq 3:Wk 4:bk 5:Wv 6:bv (size-checked for safety).
    int ix = 0, iw = -1, ib = -1;
    for (int i = 0; i < n_in; ++i) {
        if      (in_sizes[i] == 8388608) ix = i;
        else if (in_sizes[i] == 65536)   iw = i;   // keeps last (= Wv)
        else if (in_sizes[i] == 64)      ib = i;   // keeps last (= bv)
    }
    if (iw < 0) iw = 5;
    if (ib < 0) ib = 6;

    const float* x  = (const float*)d_in[ix];
    const float* Wv = (const float*)d_in[iw];
    const float* bv = (const float*)d_in[ib];
    short* wbf = (short*)d_ws;                 // 128 KB scratch
    float* out = (float*)d_out;

    cvt_w_kernel<<<64, 256, 0, stream>>>(Wv, wbf);
    vproj_kernel<<<512, 256, 0, stream>>>(x, wbf, bv, out);
}